// Round 2
// baseline (254.355 us; speedup 1.0000x reference)
//
#include <hip/hip_runtime.h>

// ---------------------------------------------------------------------------
// CESLayer: out[b,o] = cos(x@angle^T + bias) * exp(x@log|w|^T)
// B=262144, I=O=128. Memory floor ~32-42us.
// R5: attack the LDS pipe + serialization found in R4's counters
// (MfmaUtil 22% == exactly the 20us MFMA floor; LDS pipe ~22us busy with
//  4.19M conflict cycles; nothing overlapped).
//   - 256 threads = 4 waves; wave w owns 32 O-cols (128 VGPR weights, AGPR-
//     resident under the 256-reg tier of __launch_bounds__(256,2)).
//     LDS read multiplier drops 8 -> 4 (each wave re-reads the staged tile).
//   - stage path: each thread loads 8 consecutive floats (2 float4), emits
//     one 16B hi line + one 16B lo line as swizzled ds_write_b128.
//     R4's uint2 writes hit only EVEN banks (2-way conflict on every write).
//   - per wave per iter: 48 MFMAs over 4 independent acc chains.
//   - 2 blocks/CU with independent barriers -> cross-block overlap of
//     MFMA phase vs stage/epilogue phases.
// ---------------------------------------------------------------------------

typedef __attribute__((ext_vector_type(8))) short bf16x8;   // 8 bf16 = 4 VGPRs
typedef __attribute__((ext_vector_type(4))) float f32x4;

#define MFMA(a, b, c) __builtin_amdgcn_mfma_f32_16x16x32_bf16((a), (b), (c), 0, 0, 0)

__device__ __forceinline__ unsigned short f2bf_rne(float f) {
    unsigned u = __float_as_uint(f);
    unsigned r = u + 0x7FFFu + ((u >> 16) & 1u);
    return (unsigned short)(r >> 16);
}

// Split fp32 -> bf16 hi (truncated) + bf16 lo (RNE of exact residual).
__device__ __forceinline__ void bf16_split(float f, unsigned short& hi, unsigned short& lo) {
    unsigned uh = __float_as_uint(f) & 0xFFFF0000u;
    hi = (unsigned short)(uh >> 16);
    lo = f2bf_rne(f - __uint_as_float(uh));
}

// Pack two floats into one dword of bf16-hi (low=f0) and one of bf16-lo.
__device__ __forceinline__ void cvt_pair(float f0, float f1, unsigned& h, unsigned& l) {
    unsigned u0 = __float_as_uint(f0), u1 = __float_as_uint(f1);
    unsigned uh0 = u0 & 0xFFFF0000u, uh1 = u1 & 0xFFFF0000u;
    h = (uh0 >> 16) | uh1;
    float r0 = f0 - __uint_as_float(uh0);
    float r1 = f1 - __uint_as_float(uh1);
    unsigned v0 = __float_as_uint(r0), v1 = __float_as_uint(r1);
    v0 = v0 + 0x7FFFu + ((v0 >> 16) & 1u);
    v1 = v1 + 0x7FFFu + ((v1 >> 16) & 1u);
    l = (v0 >> 16) | (v1 & 0xFFFF0000u);
}

// ---------------------------------------------------------------------------
// Prep: angle=atan2(wi,wr), logmag=0.5*log(wr^2+wi^2), bf16 hi/lo split.
// ws layout (ushort): [0:16K) ang_hi [16K:32K) ang_lo [32K:48K) lg_hi [48K:64K) lg_lo
// ---------------------------------------------------------------------------
__global__ void ces_prep(const float* __restrict__ wr, const float* __restrict__ wi,
                         unsigned short* __restrict__ wsplit) {
    int idx = blockIdx.x * 256 + threadIdx.x;   // 0..16383
    float a = wr[idx], b = wi[idx];
    float r2 = a * a + b * b;
    float ang = atan2f(b, a);
    float lg = 0.5f * logf(r2);
    unsigned short ah, al, gh, gl;
    bf16_split(ang, ah, al);
    bf16_split(lg, gh, gl);
    wsplit[idx]         = ah;
    wsplit[16384 + idx] = al;
    wsplit[32768 + idx] = gh;
    wsplit[49152 + idx] = gl;
}

// ---------------------------------------------------------------------------
// Main. 256 threads = 4 waves; wave w owns O-cols [32w, 32w+32).
// MFMA 16x16x32 bf16 layouts (verified R1/R2): A: m=lane&15, k=quad*8+j;
// B: n=lane&15, k=quad*8+j; C/D: col=lane&15, row=quad*4+reg.
// LDS per buffer (8KB): hi[16][128] bf16 at +0, lo at +4096. Buf1 at +8192.
// Swizzle (write AND read): byte ^= (row&7)<<4 within the 256B row.
// ---------------------------------------------------------------------------
#define NT 16   // 16-row tiles per block; grid 1024 -> 16384 tiles total

__global__ __launch_bounds__(256, 2) void ces_main(
        const float* __restrict__ x,
        const unsigned short* __restrict__ wsplit,
        const float* __restrict__ bias,
        float* __restrict__ out) {
    __shared__ __align__(16) unsigned short smem[8192];   // 16 KiB, 2 buffers
    char* smemb = (char*)smem;

    const int tid  = threadIdx.x;
    const int wave = tid >> 6;          // 0..3
    const int lane = tid & 63;
    const int quad = lane >> 4;
    const int l16  = lane & 15;
    const int n0   = wave * 32;

    // ---- weight fragments into registers (once per block): 128 regs/wave ----
    bf16x8 wa_h[2][4], wa_l[2][4], wg_h[2][4], wg_l[2][4];
#pragma unroll
    for (int nt = 0; nt < 2; ++nt) {
        const int o = n0 + nt * 16 + l16;
#pragma unroll
        for (int ks = 0; ks < 4; ++ks) {
            const int off = o * 128 + ks * 32 + quad * 8;
            wa_h[nt][ks] = *(const bf16x8*)(wsplit + off);
            wa_l[nt][ks] = *(const bf16x8*)(wsplit + 16384 + off);
            wg_h[nt][ks] = *(const bf16x8*)(wsplit + 32768 + off);
            wg_l[nt][ks] = *(const bf16x8*)(wsplit + 49152 + off);
        }
    }
    float bias_v[2];
    bias_v[0] = bias[n0 + l16];
    bias_v[1] = bias[n0 + 16 + l16];

    // ---- stage mapping: thread t owns row t>>4, k-chunk (t&15)*8 floats ----
    const int srow = tid >> 4;                 // 0..15
    const int schk = tid & 15;                 // 0..15
    const int wb = (srow * 256 + schk * 16) ^ ((srow & 7) << 4);   // hi byte addr

    // read: A-frag lane l: row=l16, k-bytes ks*64 + quad*16, 16B
    int rb[4];
#pragma unroll
    for (int ks = 0; ks < 4; ++ks)
        rb[ks] = (l16 * 256 + ks * 64 + quad * 16) ^ ((l16 & 7) << 4);

    const float* xb = x + (size_t)blockIdx.x * (NT * 2048) + srow * 128 + schk * 8;

    // ---- prologue: stage tile 0 into buf0, prefetch tile 1 ----
    {
        float4 v0 = *(const float4*)(xb);
        float4 v1 = *(const float4*)(xb + 4);
        unsigned h0, l0, h1, l1, h2, l2, h3, l3;
        cvt_pair(v0.x, v0.y, h0, l0);
        cvt_pair(v0.z, v0.w, h1, l1);
        cvt_pair(v1.x, v1.y, h2, l2);
        cvt_pair(v1.z, v1.w, h3, l3);
        *(uint4*)(smemb + wb)        = make_uint4(h0, h1, h2, h3);
        *(uint4*)(smemb + wb + 4096) = make_uint4(l0, l1, l2, l3);
    }
    float4 pf0 = *(const float4*)(xb + 2048);
    float4 pf1 = *(const float4*)(xb + 2048 + 4);
    __syncthreads();

    for (int i = 0; i < NT; ++i) {
        const int bo = (i & 1) << 13;

        // ---- MFMA: K=128 in 4 steps, 12 MFMAs each (3-term hi/lo x 2 nt x 2 gemms)
        f32x4 accY[2], accG[2];
        accY[0] = (f32x4){0.f, 0.f, 0.f, 0.f};
        accY[1] = (f32x4){0.f, 0.f, 0.f, 0.f};
        accG[0] = (f32x4){0.f, 0.f, 0.f, 0.f};
        accG[1] = (f32x4){0.f, 0.f, 0.f, 0.f};
#pragma unroll
        for (int ks = 0; ks < 4; ++ks) {
            bf16x8 a_h = *(const bf16x8*)(smemb + (bo + rb[ks]));
            bf16x8 a_l = *(const bf16x8*)(smemb + (bo + rb[ks] + 4096));
            accY[0] = MFMA(a_h, wa_h[0][ks], accY[0]);
            accG[0] = MFMA(a_h, wg_h[0][ks], accG[0]);
            accY[1] = MFMA(a_h, wa_h[1][ks], accY[1]);
            accG[1] = MFMA(a_h, wg_h[1][ks], accG[1]);
            accY[0] = MFMA(a_h, wa_l[0][ks], accY[0]);
            accG[0] = MFMA(a_h, wg_l[0][ks], accG[0]);
            accY[1] = MFMA(a_h, wa_l[1][ks], accY[1]);
            accG[1] = MFMA(a_h, wg_l[1][ks], accG[1]);
            accY[0] = MFMA(a_l, wa_h[0][ks], accY[0]);
            accG[0] = MFMA(a_l, wg_h[0][ks], accG[0]);
            accY[1] = MFMA(a_l, wa_h[1][ks], accY[1]);
            accG[1] = MFMA(a_l, wg_h[1][ks], accG[1]);
        }

        // ---- stage tile i+1 (held in pf) into the other buffer ----
        if (i + 1 < NT) {
            const int nbo = bo ^ 8192;
            unsigned h0, l0, h1, l1, h2, l2, h3, l3;
            cvt_pair(pf0.x, pf0.y, h0, l0);
            cvt_pair(pf0.z, pf0.w, h1, l1);
            cvt_pair(pf1.x, pf1.y, h2, l2);
            cvt_pair(pf1.z, pf1.w, h3, l3);
            *(uint4*)(smemb + (nbo + wb))        = make_uint4(h0, h1, h2, h3);
            *(uint4*)(smemb + (nbo + wb + 4096)) = make_uint4(l0, l1, l2, l3);
        }
        // ---- prefetch tile i+2 (clamped: tail iters redundantly reload) ----
        {
            int tn = i + 2;
            if (tn > NT - 1) tn = NT - 1;
            pf0 = *(const float4*)(xb + tn * 2048);
            pf1 = *(const float4*)(xb + tn * 2048 + 4);
        }
        __syncthreads();

        // ---- epilogue tile i: stores after barrier overlap next iter's work ----
        {
            const size_t R0 = (size_t)(blockIdx.x * NT + i) * 16;
#pragma unroll
            for (int nt = 0; nt < 2; ++nt) {
                const int o = n0 + nt * 16 + l16;
#pragma unroll
                for (int r = 0; r < 4; ++r) {
                    float y = accY[nt][r] + bias_v[nt];
                    out[(R0 + quad * 4 + r) * 128 + o] = __cosf(y) * __expf(accG[nt][r]);
                }
            }
        }
    }
}

extern "C" void kernel_launch(void* const* d_in, const int* in_sizes, int n_in,
                              void* d_out, int out_size, void* d_ws, size_t ws_size,
                              hipStream_t stream) {
    const float* x    = (const float*)d_in[0];
    const float* wr   = (const float*)d_in[1];
    const float* wi   = (const float*)d_in[2];
    const float* bias = (const float*)d_in[3];
    float* out = (float*)d_out;
    unsigned short* wsplit = (unsigned short*)d_ws;   // 128 KiB

    ces_prep<<<64, 256, 0, stream>>>(wr, wi, wsplit);

    ces_main<<<1024, 256, 0, stream>>>(x, wsplit, bias, out);
}